// Round 1
// baseline (2087.577 us; speedup 1.0000x reference)
//
#include <hip/hip_runtime.h>
#include <math.h>

#define NAG 8
#define NE  16
#define ED  64
#define HYPD 128
#define NH  4
#define HD  32
#define QKVW 384
#define QKVP 388   // padded LDS row stride for qkv (breaks bank alignment)
#define NTHR 384

__device__ __forceinline__ float4 f4load(const float* p) {
    return *reinterpret_cast<const float4*>(p);
}
__device__ __forceinline__ void f4store(float* p, const float4& v) {
    *reinterpret_cast<float4*>(p) = v;
}
__device__ __forceinline__ void f4fma(float4& a, float s, const float4& w) {
    a.x += s * w.x; a.y += s * w.y; a.z += s * w.z; a.w += s * w.w;
}

__global__ __launch_bounds__(NTHR) void flexqmixer_kernel(
    const float* __restrict__ agent_qs,    // [B,8]
    const float* __restrict__ entities,    // [B,16,64]
    const int*   __restrict__ entity_mask, // [B,16]
    const float* __restrict__ fc1_w,       // [4,64,128]
    const float* __restrict__ fc1_b,       // [4,128]
    const float* __restrict__ attn_w,      // [4,128,384]
    const float* __restrict__ out_w,       // [4,128,128]
    const float* __restrict__ out_b,       // [4,128]
    const float* __restrict__ fc2_w,       // [4,128,32]
    const float* __restrict__ fc2_b,       // [4,32]
    float* __restrict__ out)               // [B]
{
    const int b   = blockIdx.x;
    const int tid = threadIdx.x;

    __shared__ float s_ent[NE][ED];        // 4 KB
    __shared__ float s_x1t[HYPD][NE];      // 8 KB  x1 transposed: [d][e]
    __shared__ float s_qkv[NE][QKVP];      // ~24.8 KB
    __shared__ float s_w[NH][NAG][NE];     // 2 KB  logits -> attn weights
    __shared__ float s_attn[NAG][HYPD];    // 4 KB
    __shared__ float s_attnout[NAG][HYPD]; // 4 KB
    __shared__ float s_outs[4][NAG][32];   // 4 KB
    __shared__ float s_mask[NE];
    __shared__ float s_qs[NAG];

    // ---- stage per-sample inputs ----
    const float* ent = entities + (size_t)b * NE * ED;
    for (int o = tid; o < NE * ED; o += NTHR)
        s_ent[o >> 6][o & 63] = ent[o];
    if (tid < NE)
        s_mask[tid] = (entity_mask[(size_t)b * NE + tid] != 0) ? 1.0f : 0.0f;
    if (tid < NAG)
        s_qs[tid] = agent_qs[(size_t)b * NAG + tid];
    __syncthreads();

    for (int i = 0; i < 4; ++i) {
        // ---- step 1: x1 = relu(ent @ fc1_w + fc1_b), stored transposed ----
        {
            const float* W1 = fc1_w + i * ED * HYPD;
            const float* B1 = fc1_b + i * HYPD;
            for (int o4 = tid; o4 < 512; o4 += NTHR) {
                int e = o4 >> 5;
                int j = (o4 & 31) * 4;
                float4 acc = f4load(B1 + j);
                for (int d = 0; d < ED; ++d) {
                    float x = s_ent[e][d];
                    float4 w = f4load(W1 + d * HYPD + j);
                    f4fma(acc, x, w);
                }
                s_x1t[j + 0][e] = fmaxf(acc.x, 0.f);
                s_x1t[j + 1][e] = fmaxf(acc.y, 0.f);
                s_x1t[j + 2][e] = fmaxf(acc.z, 0.f);
                s_x1t[j + 3][e] = fmaxf(acc.w, 0.f);
            }
        }
        __syncthreads();

        // ---- step 2: qkv = x1 @ attn_w  (register-blocked over 4 e's) ----
        {
            const float* W2 = attn_w + i * HYPD * QKVW;
            int j  = (tid % 96) * 4;
            int e0 = (tid / 96) * 4;
            float4 a0 = {0,0,0,0}, a1 = {0,0,0,0}, a2 = {0,0,0,0}, a3 = {0,0,0,0};
            for (int d = 0; d < HYPD; ++d) {
                float4 w = f4load(W2 + d * QKVW + j);
                float4 x = f4load(&s_x1t[d][e0]);
                f4fma(a0, x.x, w);
                f4fma(a1, x.y, w);
                f4fma(a2, x.z, w);
                f4fma(a3, x.w, w);
            }
            f4store(&s_qkv[e0 + 0][j], a0);
            f4store(&s_qkv[e0 + 1][j], a1);
            f4store(&s_qkv[e0 + 2][j], a2);
            f4store(&s_qkv[e0 + 3][j], a3);
        }
        __syncthreads();

        // ---- step 3: logits[h][q][k] = (q . k) / sqrt(32) ----
        {
            const float inv_scale = 0.17677669529663687f; // 1/sqrt(32)
            for (int o = tid; o < 512; o += NTHR) {
                int h  = o >> 7;
                int qi = (o >> 4) & 7;
                int k  = o & 15;
                const float* qp = &s_qkv[qi][h * HD];
                const float* kp = &s_qkv[k][HYPD + h * HD];
                float s = 0.f;
                #pragma unroll
                for (int d4 = 0; d4 < 8; ++d4) {
                    float4 q  = f4load(qp + 4 * d4);
                    float4 kk = f4load(kp + 4 * d4);
                    s += q.x * kk.x + q.y * kk.y + q.z * kk.z + q.w * kk.w;
                }
                s_w[h][qi][k] = s * inv_scale;
            }
        }
        __syncthreads();

        // ---- step 4: masked softmax per (h, q) row ----
        if (tid < 32) {
            int h  = tid >> 3;
            int qi = tid & 7;
            float am = s_mask[qi];
            float mx = -3.0e38f;
            bool any = false;
            #pragma unroll
            for (int k = 0; k < NE; ++k) {
                if (s_mask[k] == 0.f) { any = true; mx = fmaxf(mx, s_w[h][qi][k]); }
            }
            if (am != 0.f || !any) {
                #pragma unroll
                for (int k = 0; k < NE; ++k) s_w[h][qi][k] = 0.f;
            } else {
                float ebuf[NE];
                float sum = 0.f;
                #pragma unroll
                for (int k = 0; k < NE; ++k) {
                    float e = (s_mask[k] == 0.f) ? __expf(s_w[h][qi][k] - mx) : 0.f;
                    ebuf[k] = e;
                    sum += e;
                }
                float inv = 1.f / sum;
                #pragma unroll
                for (int k = 0; k < NE; ++k) s_w[h][qi][k] = ebuf[k] * inv;
            }
        }
        __syncthreads();

        // ---- step 5: attn[q][h*32+d] = sum_k w[h][q][k] * v[k][h*32+d] ----
        if (tid < 256) {
            int qi = tid >> 5;
            int j  = (tid & 31) * 4;
            int h  = j >> 5;
            int d0 = j & 31;
            float4 acc = {0,0,0,0};
            #pragma unroll
            for (int k = 0; k < NE; ++k) {
                float w = s_w[h][qi][k];
                float4 v = f4load(&s_qkv[k][2 * HYPD + h * HD + d0]);
                f4fma(acc, w, v);
            }
            f4store(&s_attn[qi][j], acc);
        }
        __syncthreads();

        // ---- step 6: attnout = (attn @ out_w + out_b) * keep ----
        {
            const float* W3 = out_w + i * HYPD * HYPD;
            const float* B3 = out_b + i * HYPD;
            if (tid < 256) {
                int qi = tid >> 5;
                int j  = (tid & 31) * 4;
                float4 acc = f4load(B3 + j);
                for (int d = 0; d < HYPD; ++d) {
                    float a = s_attn[qi][d];
                    float4 w = f4load(W3 + d * HYPD + j);
                    f4fma(acc, a, w);
                }
                float keep = 1.f - s_mask[qi];
                acc.x *= keep; acc.y *= keep; acc.z *= keep; acc.w *= keep;
                f4store(&s_attnout[qi][j], acc);
            }
        }
        __syncthreads();

        // ---- step 7: outs[i] = (attnout @ fc2_w + fc2_b) * keep ----
        {
            const float* W4 = fc2_w + i * HYPD * 32;
            const float* B4 = fc2_b + i * 32;
            if (tid < 64) {
                int qi = tid >> 3;
                int c  = (tid & 7) * 4;
                float4 acc = f4load(B4 + c);
                for (int d = 0; d < HYPD; ++d) {
                    float a = s_attnout[qi][d];
                    float4 w = f4load(W4 + d * 32 + c);
                    f4fma(acc, a, w);
                }
                float keep = 1.f - s_mask[qi];
                acc.x *= keep; acc.y *= keep; acc.z *= keep; acc.w *= keep;
                f4store(&s_outs[i][qi][c], acc);
            }
        }
        __syncthreads();
    }

    // ---- final mixing stage on lanes 0..31 ----
    if (tid < 32) {
        const int c = tid;
        float b1 = 0.f, s1 = 0.f, vs = 0.f;
        #pragma unroll
        for (int qi = 0; qi < NAG; ++qi) {
            b1 += s_outs[2][qi][c];
            s1 += s_outs[1][qi][c];
            vs += s_outs[3][qi][c];
        }
        b1 *= 0.125f;
        s1 *= 0.125f;

        // hidden[c] = elu( sum_a qs[a] * softmax_c(outs0[a])[c] + b1[c] )
        float hid = 0.f;
        #pragma unroll
        for (int a = 0; a < NAG; ++a) {
            float x = s_outs[0][a][c];
            float mx = x;
            #pragma unroll
            for (int m = 16; m >= 1; m >>= 1) mx = fmaxf(mx, __shfl_xor(mx, m, 32));
            float e = __expf(x - mx);
            float s = e;
            #pragma unroll
            for (int m = 16; m >= 1; m >>= 1) s += __shfl_xor(s, m, 32);
            hid += s_qs[a] * (e / s);
        }
        hid += b1;
        hid = (hid > 0.f) ? hid : expm1f(hid);

        // w_final[c] = softmax_c(mean_q outs1)
        float mx = s1;
        #pragma unroll
        for (int m = 16; m >= 1; m >>= 1) mx = fmaxf(mx, __shfl_xor(mx, m, 32));
        float e = __expf(s1 - mx);
        float ssum = e;
        #pragma unroll
        for (int m = 16; m >= 1; m >>= 1) ssum += __shfl_xor(ssum, m, 32);
        float wf = e / ssum;

        float red = hid * wf + vs * (1.f / 256.f);
        #pragma unroll
        for (int m = 16; m >= 1; m >>= 1) red += __shfl_xor(red, m, 32);
        if (tid == 0) out[b] = red;
    }
}

extern "C" void kernel_launch(void* const* d_in, const int* in_sizes, int n_in,
                              void* d_out, int out_size, void* d_ws, size_t ws_size,
                              hipStream_t stream) {
    const float* agent_qs    = (const float*)d_in[0];
    const float* entities    = (const float*)d_in[1];
    const int*   entity_mask = (const int*)  d_in[2];
    const float* fc1_w       = (const float*)d_in[3];
    const float* fc1_b       = (const float*)d_in[4];
    const float* attn_w      = (const float*)d_in[5];
    const float* out_w       = (const float*)d_in[6];
    const float* out_b       = (const float*)d_in[7];
    const float* fc2_w       = (const float*)d_in[8];
    const float* fc2_b       = (const float*)d_in[9];
    float* out = (float*)d_out;

    const int B = in_sizes[0] / NAG;  // 8192

    flexqmixer_kernel<<<B, NTHR, 0, stream>>>(
        agent_qs, entities, entity_mask,
        fc1_w, fc1_b, attn_w, out_w, out_b, fc2_w, fc2_b, out);
}

// Round 2
// 297.919 us; speedup vs baseline: 7.0072x; 7.0072x over previous
//
#include <hip/hip_runtime.h>
#include <math.h>

#define NAG 8
#define NE  16
#define ED  64
#define HYPD 128
#define QKVW 384
#define SB 4

typedef __attribute__((ext_vector_type(8))) short bf16x8;
typedef __attribute__((ext_vector_type(4))) short bf16x4;
typedef __attribute__((ext_vector_type(4))) float f32x4;

__device__ __forceinline__ short f2bf(float f) {
    union { float f; unsigned u; } c; c.f = f;
    unsigned r = (c.u + 0x7FFFu + ((c.u >> 16) & 1u)) >> 16;
    return (short)r;
}
__device__ __forceinline__ float bflo(unsigned u) {
    union { unsigned u; float f; } c; c.u = u << 16; return c.f;
}
__device__ __forceinline__ float bfhi(unsigned u) {
    union { unsigned u; float f; } c; c.u = u & 0xFFFF0000u; return c.f;
}
__device__ __forceinline__ float bf2f(short s) {
    union { unsigned u; float f; } c; c.u = ((unsigned)(unsigned short)s) << 16; return c.f;
}

// ---------------- weight packing: fp32 -> bf16 MFMA B-fragments -------------
// slot map: fc1 [0,64) = h*16+nt*2+kt ; attn [64,448) = 64+h*96+nt*4+kt ;
//           out [448,576) = 448+h*32+nt*4+kt ; fc2 [576,608) = 576+h*8+nt*4+kt
// frag elem j of lane l: k = kt*32 + 4*(l>>4) + (j&3) + 16*(j>>2), n = nt*16 + (l&15)
__global__ void pack_weights(const float* __restrict__ fc1_w,
                             const float* __restrict__ attn_w,
                             const float* __restrict__ out_w,
                             const float* __restrict__ fc2_w,
                             short* __restrict__ ws) {
    int gid = blockIdx.x * 256 + threadIdx.x;
    if (gid >= 608 * 64) return;
    int slot = gid >> 6, l = gid & 63;
    const float* src; int N, nt, kt;
    if (slot < 64) {
        int h = slot >> 4, f = slot & 15;
        nt = f >> 1; kt = f & 1; N = HYPD; src = fc1_w + h * ED * HYPD;
    } else if (slot < 448) {
        int s2 = slot - 64; int h = s2 / 96, f = s2 % 96;
        nt = f >> 2; kt = f & 3; N = QKVW; src = attn_w + h * HYPD * QKVW;
    } else if (slot < 576) {
        int s2 = slot - 448; int h = s2 >> 5, f = s2 & 31;
        nt = f >> 2; kt = f & 3; N = HYPD; src = out_w + h * HYPD * HYPD;
    } else {
        int s2 = slot - 576; int h = s2 >> 3, f = s2 & 7;
        nt = f >> 2; kt = f & 3; N = 32; src = fc2_w + h * HYPD * 32;
    }
    int rg = l >> 4, lc = l & 15;
    bf16x8 fr;
    #pragma unroll
    for (int j = 0; j < 8; ++j) {
        int k = kt * 32 + 4 * rg + (j & 3) + 16 * (j >> 2);
        fr[j] = f2bf(src[k * N + nt * 16 + lc]);
    }
    ((bf16x8*)ws)[slot * 64 + l] = fr;
}

// ---------------- fused MFMA kernel: 4 samples / block, 256 threads ---------
// LDS arena (bytes):
//  [0      ,16896) x1[64][132] bf16   (overlaid later: logits f32[512]@0, attn[32][132]@8192)
//  [16896  ,49920) kv[64][258] bf16 (k cols 0..127, v cols 128..255) (attn2[32][132]@16896)
//  [49920  ,58240) q[32][130] bf16
//  [58240  ,60288) out0[32][32] bf16
//  [60288  ,61824) means[3][4][32] f32
//  [61824  ,62080) em[64] f32
#define X1S 132
#define KVS 258
#define QS  130
#define LDS_BYTES 62080

__global__ __launch_bounds__(256, 2) void flexq_mfma(
    const float* __restrict__ agent_qs,
    const float* __restrict__ entities,
    const int*   __restrict__ entity_mask,
    const float* __restrict__ fc1_b,
    const float* __restrict__ out_b,
    const float* __restrict__ fc2_b,
    const short* __restrict__ wfrag,
    float* __restrict__ out, int B)
{
    __shared__ __align__(16) char smem[LDS_BYTES];
    short* x1    = (short*)(smem);
    float* slog  = (float*)(smem);
    short* attn  = (short*)(smem + 8192);
    short* kv    = (short*)(smem + 16896);
    short* attn2 = (short*)(smem + 16896);
    short* q     = (short*)(smem + 49920);
    short* out0  = (short*)(smem + 58240);
    float* means = (float*)(smem + 60288);
    float* em    = (float*)(smem + 61824);

    const int tid = threadIdx.x;
    const int l = tid & 63, w = tid >> 6;
    const int rg = l >> 4, lc = l & 15;
    const int b4 = blockIdx.x * SB;
    const bf16x8* WF = (const bf16x8*)wfrag;

    if (tid < 64)
        em[tid] = (entity_mask[(size_t)b4 * NE + tid] != 0) ? 1.0f : 0.0f;

    for (int i = 0; i < 4; ++i) {
        // ---------- P1: x1 = relu(ent @ fc1_w + fc1_b) ----------
        {
            f32x4 acc[4][2];
            #pragma unroll
            for (int mt = 0; mt < 4; ++mt) {
                acc[mt][0] = (f32x4){0.f,0.f,0.f,0.f};
                acc[mt][1] = (f32x4){0.f,0.f,0.f,0.f};
            }
            #pragma unroll
            for (int kt = 0; kt < 2; ++kt) {
                bf16x8 b0 = WF[(i*16 + (2*w+0)*2 + kt)*64 + l];
                bf16x8 b1 = WF[(i*16 + (2*w+1)*2 + kt)*64 + l];
                #pragma unroll
                for (int mt = 0; mt < 4; ++mt) {
                    const float* ap = entities + ((size_t)(b4 + mt) * NE + lc) * ED + kt*32 + rg*4;
                    float4 lo = *(const float4*)ap;
                    float4 hi = *(const float4*)(ap + 16);
                    bf16x8 af;
                    af[0]=f2bf(lo.x); af[1]=f2bf(lo.y); af[2]=f2bf(lo.z); af[3]=f2bf(lo.w);
                    af[4]=f2bf(hi.x); af[5]=f2bf(hi.y); af[6]=f2bf(hi.z); af[7]=f2bf(hi.w);
                    acc[mt][0] = __builtin_amdgcn_mfma_f32_16x16x32_bf16(af, b0, acc[mt][0], 0,0,0);
                    acc[mt][1] = __builtin_amdgcn_mfma_f32_16x16x32_bf16(af, b1, acc[mt][1], 0,0,0);
                }
            }
            float bias0 = fc1_b[i*HYPD + 32*w + lc];
            float bias1 = fc1_b[i*HYPD + 32*w + 16 + lc];
            #pragma unroll
            for (int mt = 0; mt < 4; ++mt)
                #pragma unroll
                for (int r = 0; r < 4; ++r) {
                    int row = 16*mt + 4*rg + r;
                    x1[row*X1S + 32*w + lc]      = f2bf(fmaxf(acc[mt][0][r] + bias0, 0.f));
                    x1[row*X1S + 32*w + 16 + lc] = f2bf(fmaxf(acc[mt][1][r] + bias1, 0.f));
                }
        }
        __syncthreads();

        // ---------- P2: qkv = x1 @ attn_w (wave w owns N-cols 96w..96w+95) ----------
        {
            f32x4 acc[4][6];
            #pragma unroll
            for (int mt = 0; mt < 4; ++mt)
                #pragma unroll
                for (int n = 0; n < 6; ++n) acc[mt][n] = (f32x4){0.f,0.f,0.f,0.f};
            #pragma unroll
            for (int kt = 0; kt < 4; ++kt) {
                bf16x8 a[4];
                #pragma unroll
                for (int mt = 0; mt < 4; ++mt) {
                    int base = (16*mt + lc)*X1S + kt*32 + rg*4;
                    bf16x4 lo = *(const bf16x4*)(x1 + base);
                    bf16x4 hi = *(const bf16x4*)(x1 + base + 16);
                    a[mt][0]=lo[0]; a[mt][1]=lo[1]; a[mt][2]=lo[2]; a[mt][3]=lo[3];
                    a[mt][4]=hi[0]; a[mt][5]=hi[1]; a[mt][6]=hi[2]; a[mt][7]=hi[3];
                }
                #pragma unroll
                for (int n = 0; n < 6; ++n) {
                    bf16x8 bfr = WF[(64 + i*96 + (6*w+n)*4 + kt)*64 + l];
                    #pragma unroll
                    for (int mt = 0; mt < 4; ++mt)
                        acc[mt][n] = __builtin_amdgcn_mfma_f32_16x16x32_bf16(a[mt], bfr, acc[mt][n], 0,0,0);
                }
            }
            #pragma unroll
            for (int n = 0; n < 6; ++n) {
                int col = (6*w + n) * 16 + lc;
                #pragma unroll
                for (int mt = 0; mt < 4; ++mt)
                    #pragma unroll
                    for (int r = 0; r < 4; ++r) {
                        int row = 16*mt + 4*rg + r;
                        short v = f2bf(acc[mt][n][r]);
                        if (col < HYPD) {              // q: only agent rows (e<8)
                            if (rg < 2) q[(mt*8 + 4*rg + r)*QS + col] = v;
                        } else if (col < 2*HYPD) {     // k
                            kv[row*KVS + (col - HYPD)] = v;
                        } else {                       // v
                            kv[row*KVS + 128 + (col - 2*HYPD)] = v;
                        }
                    }
            }
        }
        __syncthreads();

        // ---------- P3a: logits ----------
        {
            int s = tid >> 6, h = (tid >> 4) & 3, qi = (tid >> 1) & 7, kh = tid & 1;
            const unsigned* qp = (const unsigned*)(q + (s*NAG + qi)*QS + h*32);
            float qv[32];
            #pragma unroll
            for (int x = 0; x < 16; ++x) { unsigned u = qp[x]; qv[2*x] = bflo(u); qv[2*x+1] = bfhi(u); }
            #pragma unroll
            for (int kk = 0; kk < 8; ++kk) {
                int k = kh*8 + kk;
                const unsigned* kp = (const unsigned*)(kv + (s*NE + k)*KVS + h*32);
                float sd = 0.f;
                #pragma unroll
                for (int x = 0; x < 16; ++x) { unsigned u = kp[x]; sd += qv[2*x]*bflo(u) + qv[2*x+1]*bfhi(u); }
                slog[((s*4 + h)*NAG + qi)*16 + k] = sd * 0.17677669529663687f;
            }
        }
        __syncthreads();

        // ---------- P3b: masked softmax ----------
        if (tid < 128) {
            int s = tid >> 5, h = (tid >> 3) & 3, qi = tid & 7;
            float am = em[s*NE + qi];
            float* rowp = slog + ((s*4 + h)*NAG + qi)*16;
            float mx = -3.0e38f; bool any = false;
            #pragma unroll
            for (int k = 0; k < NE; ++k)
                if (em[s*NE + k] == 0.f) { any = true; mx = fmaxf(mx, rowp[k]); }
            if (am != 0.f || !any) {
                #pragma unroll
                for (int k = 0; k < NE; ++k) rowp[k] = 0.f;
            } else {
                float eb[NE]; float sum = 0.f;
                #pragma unroll
                for (int k = 0; k < NE; ++k) {
                    float e = (em[s*NE + k] == 0.f) ? __expf(rowp[k] - mx) : 0.f;
                    eb[k] = e; sum += e;
                }
                float inv = 1.f / sum;
                #pragma unroll
                for (int k = 0; k < NE; ++k) rowp[k] = eb[k] * inv;
            }
        }
        __syncthreads();

        // ---------- P3c: PV -> attn (bf16) ----------
        {
            int r2 = tid >> 3, cg = (tid & 7) * 16;
            int s = r2 >> 3, h = cg >> 5;
            const float* wrow = slog + ((s*4 + h)*NAG + (r2 & 7))*16;
            float av[16];
            #pragma unroll
            for (int x = 0; x < 16; ++x) av[x] = 0.f;
            #pragma unroll
            for (int k = 0; k < NE; ++k) {
                float wv = wrow[k];
                const unsigned* vp = (const unsigned*)(kv + (s*NE + k)*KVS + 128 + cg);
                #pragma unroll
                for (int x = 0; x < 8; ++x) { unsigned u = vp[x]; av[2*x] += wv*bflo(u); av[2*x+1] += wv*bfhi(u); }
            }
            unsigned* dst = (unsigned*)(attn + r2*X1S + cg);
            #pragma unroll
            for (int x = 0; x < 8; ++x)
                dst[x] = ((unsigned)(unsigned short)f2bf(av[2*x])) |
                         (((unsigned)(unsigned short)f2bf(av[2*x+1])) << 16);
        }
        __syncthreads();

        // ---------- P4: attn2 = (attn @ out_w + out_b) * keep ----------
        {
            f32x4 acc[2][2];
            #pragma unroll
            for (int mt = 0; mt < 2; ++mt) { acc[mt][0] = (f32x4){0.f,0.f,0.f,0.f}; acc[mt][1] = (f32x4){0.f,0.f,0.f,0.f}; }
            #pragma unroll
            for (int kt = 0; kt < 4; ++kt) {
                bf16x8 a[2];
                #pragma unroll
                for (int mt = 0; mt < 2; ++mt) {
                    int base = (16*mt + lc)*X1S + kt*32 + rg*4;
                    bf16x4 lo = *(const bf16x4*)(attn + base);
                    bf16x4 hi = *(const bf16x4*)(attn + base + 16);
                    a[mt][0]=lo[0]; a[mt][1]=lo[1]; a[mt][2]=lo[2]; a[mt][3]=lo[3];
                    a[mt][4]=hi[0]; a[mt][5]=hi[1]; a[mt][6]=hi[2]; a[mt][7]=hi[3];
                }
                bf16x8 b0 = WF[(448 + i*32 + (2*w+0)*4 + kt)*64 + l];
                bf16x8 b1 = WF[(448 + i*32 + (2*w+1)*4 + kt)*64 + l];
                #pragma unroll
                for (int mt = 0; mt < 2; ++mt) {
                    acc[mt][0] = __builtin_amdgcn_mfma_f32_16x16x32_bf16(a[mt], b0, acc[mt][0], 0,0,0);
                    acc[mt][1] = __builtin_amdgcn_mfma_f32_16x16x32_bf16(a[mt], b1, acc[mt][1], 0,0,0);
                }
            }
            float bias0 = out_b[i*HYPD + 32*w + lc];
            float bias1 = out_b[i*HYPD + 32*w + 16 + lc];
            #pragma unroll
            for (int mt = 0; mt < 2; ++mt)
                #pragma unroll
                for (int r = 0; r < 4; ++r) {
                    int row = 16*mt + 4*rg + r;
                    float keep = 1.f - em[(row >> 3)*NE + (row & 7)];
                    attn2[row*X1S + 32*w + lc]      = f2bf((acc[mt][0][r] + bias0)*keep);
                    attn2[row*X1S + 32*w + 16 + lc] = f2bf((acc[mt][1][r] + bias1)*keep);
                }
        }
        __syncthreads();

        // ---------- P5: outs[i] = (attn2 @ fc2_w + fc2_b) * keep ----------
        {
            int mt = w >> 1, nt = w & 1;
            f32x4 acc = (f32x4){0.f,0.f,0.f,0.f};
            #pragma unroll
            for (int kt = 0; kt < 4; ++kt) {
                int base = (16*mt + lc)*X1S + kt*32 + rg*4;
                bf16x4 lo = *(const bf16x4*)(attn2 + base);
                bf16x4 hi = *(const bf16x4*)(attn2 + base + 16);
                bf16x8 a;
                a[0]=lo[0]; a[1]=lo[1]; a[2]=lo[2]; a[3]=lo[3];
                a[4]=hi[0]; a[5]=hi[1]; a[6]=hi[2]; a[7]=hi[3];
                bf16x8 bfr = WF[(576 + i*8 + nt*4 + kt)*64 + l];
                acc = __builtin_amdgcn_mfma_f32_16x16x32_bf16(a, bfr, acc, 0,0,0);
            }
            float bias = fc2_b[i*32 + nt*16 + lc];
            float vals[4];
            #pragma unroll
            for (int r = 0; r < 4; ++r) {
                int row = 16*mt + 4*rg + r;
                float keep = 1.f - em[(row >> 3)*NE + (row & 7)];
                vals[r] = (acc[r] + bias) * keep;
            }
            if (i == 0) {
                #pragma unroll
                for (int r = 0; r < 4; ++r)
                    out0[(16*mt + 4*rg + r)*32 + nt*16 + lc] = f2bf(vals[r]);
            } else {
                float ps = vals[0] + vals[1] + vals[2] + vals[3];
                ps += __shfl_xor(ps, 16);
                if ((rg & 1) == 0) {
                    int s = 2*mt + (rg >> 1);
                    means[(i-1)*128 + s*32 + nt*16 + lc] = ps;
                }
            }
        }
        __syncthreads();
    }

    // ---------- P6: mixing (wave w = sample w, lanes 0..31) ----------
    if ((tid & 63) < 32) {
        int s = w, c = tid & 31;
        float s1 = means[0*128 + s*32 + c] * 0.125f;   // mean of outs[1]
        float b1 = means[1*128 + s*32 + c] * 0.125f;   // mean of outs[2]
        float vsum = means[2*128 + s*32 + c];          // agent-sum of outs[3]

        float hid = 0.f;
        #pragma unroll
        for (int a = 0; a < NAG; ++a) {
            float x = bf2f(out0[(s*NAG + a)*32 + c]);
            float mx = x;
            #pragma unroll
            for (int m = 16; m >= 1; m >>= 1) mx = fmaxf(mx, __shfl_xor(mx, m, 32));
            float e = __expf(x - mx);
            float sum = e;
            #pragma unroll
            for (int m = 16; m >= 1; m >>= 1) sum += __shfl_xor(sum, m, 32);
            float qsv = agent_qs[(size_t)(b4 + s)*NAG + a];
            hid += qsv * (e / sum);
        }
        hid += b1;
        hid = (hid > 0.f) ? hid : expm1f(hid);

        float mx = s1;
        #pragma unroll
        for (int m = 16; m >= 1; m >>= 1) mx = fmaxf(mx, __shfl_xor(mx, m, 32));
        float e = __expf(s1 - mx);
        float ss = e;
        #pragma unroll
        for (int m = 16; m >= 1; m >>= 1) ss += __shfl_xor(ss, m, 32);
        float wf = e / ss;

        float red = hid * wf + vsum * (1.f / 256.f);
        #pragma unroll
        for (int m = 16; m >= 1; m >>= 1) red += __shfl_xor(red, m, 32);
        if (c == 0) out[b4 + s] = red;
    }
}

// ======================= fp32 fallback (verified round-1) ====================
#define QKVP 388
#define NTHR 384
__device__ __forceinline__ float4 f4load(const float* p) { return *reinterpret_cast<const float4*>(p); }
__device__ __forceinline__ void f4store(float* p, const float4& v) { *reinterpret_cast<float4*>(p) = v; }
__device__ __forceinline__ void f4fma(float4& a, float s, const float4& w) {
    a.x += s * w.x; a.y += s * w.y; a.z += s * w.z; a.w += s * w.w;
}

__global__ __launch_bounds__(NTHR) void flexq_fp32(
    const float* __restrict__ agent_qs, const float* __restrict__ entities,
    const int* __restrict__ entity_mask, const float* __restrict__ fc1_w,
    const float* __restrict__ fc1_b, const float* __restrict__ attn_w,
    const float* __restrict__ out_w, const float* __restrict__ out_b,
    const float* __restrict__ fc2_w, const float* __restrict__ fc2_b,
    float* __restrict__ out)
{
    const int b = blockIdx.x, tid = threadIdx.x;
    __shared__ float s_ent[NE][ED];
    __shared__ float s_x1t[HYPD][NE];
    __shared__ float s_qkv[NE][QKVP];
    __shared__ float s_w[4][NAG][NE];
    __shared__ float s_attn[NAG][HYPD];
    __shared__ float s_attnout[NAG][HYPD];
    __shared__ float s_outs[4][NAG][32];
    __shared__ float s_mask[NE];
    __shared__ float s_qs[NAG];

    const float* ent = entities + (size_t)b * NE * ED;
    for (int o = tid; o < NE * ED; o += NTHR) s_ent[o >> 6][o & 63] = ent[o];
    if (tid < NE) s_mask[tid] = (entity_mask[(size_t)b * NE + tid] != 0) ? 1.0f : 0.0f;
    if (tid < NAG) s_qs[tid] = agent_qs[(size_t)b * NAG + tid];
    __syncthreads();

    for (int i = 0; i < 4; ++i) {
        {
            const float* W1 = fc1_w + i * ED * HYPD;
            const float* B1 = fc1_b + i * HYPD;
            for (int o4 = tid; o4 < 512; o4 += NTHR) {
                int e = o4 >> 5, j = (o4 & 31) * 4;
                float4 acc = f4load(B1 + j);
                for (int d = 0; d < ED; ++d) { float x = s_ent[e][d]; f4fma(acc, x, f4load(W1 + d * HYPD + j)); }
                s_x1t[j+0][e] = fmaxf(acc.x, 0.f); s_x1t[j+1][e] = fmaxf(acc.y, 0.f);
                s_x1t[j+2][e] = fmaxf(acc.z, 0.f); s_x1t[j+3][e] = fmaxf(acc.w, 0.f);
            }
        }
        __syncthreads();
        {
            const float* W2 = attn_w + i * HYPD * QKVW;
            int j = (tid % 96) * 4, e0 = (tid / 96) * 4;
            float4 a0 = {0,0,0,0}, a1 = {0,0,0,0}, a2 = {0,0,0,0}, a3 = {0,0,0,0};
            for (int d = 0; d < HYPD; ++d) {
                float4 wv = f4load(W2 + d * QKVW + j);
                float4 x = f4load(&s_x1t[d][e0]);
                f4fma(a0, x.x, wv); f4fma(a1, x.y, wv); f4fma(a2, x.z, wv); f4fma(a3, x.w, wv);
            }
            f4store(&s_qkv[e0+0][j], a0); f4store(&s_qkv[e0+1][j], a1);
            f4store(&s_qkv[e0+2][j], a2); f4store(&s_qkv[e0+3][j], a3);
        }
        __syncthreads();
        {
            const float inv_scale = 0.17677669529663687f;
            for (int o = tid; o < 512; o += NTHR) {
                int h = o >> 7, qi = (o >> 4) & 7, k = o & 15;
                const float* qp = &s_qkv[qi][h * 32];
                const float* kp = &s_qkv[k][HYPD + h * 32];
                float s = 0.f;
                #pragma unroll
                for (int d4 = 0; d4 < 8; ++d4) {
                    float4 qv = f4load(qp + 4 * d4), kk = f4load(kp + 4 * d4);
                    s += qv.x*kk.x + qv.y*kk.y + qv.z*kk.z + qv.w*kk.w;
                }
                s_w[h][qi][k] = s * inv_scale;
            }
        }
        __syncthreads();
        if (tid < 32) {
            int h = tid >> 3, qi = tid & 7;
            float am = s_mask[qi];
            float mx = -3.0e38f; bool any = false;
            #pragma unroll
            for (int k = 0; k < NE; ++k)
                if (s_mask[k] == 0.f) { any = true; mx = fmaxf(mx, s_w[h][qi][k]); }
            if (am != 0.f || !any) {
                #pragma unroll
                for (int k = 0; k < NE; ++k) s_w[h][qi][k] = 0.f;
            } else {
                float eb[NE]; float sum = 0.f;
                #pragma unroll
                for (int k = 0; k < NE; ++k) {
                    float e = (s_mask[k] == 0.f) ? __expf(s_w[h][qi][k] - mx) : 0.f;
                    eb[k] = e; sum += e;
                }
                float inv = 1.f / sum;
                #pragma unroll
                for (int k = 0; k < NE; ++k) s_w[h][qi][k] = eb[k] * inv;
            }
        }
        __syncthreads();
        if (tid < 256) {
            int qi = tid >> 5, j = (tid & 31) * 4, h = j >> 5, d0 = j & 31;
            float4 acc = {0,0,0,0};
            #pragma unroll
            for (int k = 0; k < NE; ++k) f4fma(acc, s_w[h][qi][k], f4load(&s_qkv[k][2*HYPD + h*32 + d0]));
            f4store(&s_attn[qi][j], acc);
        }
        __syncthreads();
        if (tid < 256) {
            const float* W3 = out_w + i * HYPD * HYPD;
            const float* B3 = out_b + i * HYPD;
            int qi = tid >> 5, j = (tid & 31) * 4;
            float4 acc = f4load(B3 + j);
            for (int d = 0; d < HYPD; ++d) f4fma(acc, s_attn[qi][d], f4load(W3 + d * HYPD + j));
            float keep = 1.f - s_mask[qi];
            acc.x *= keep; acc.y *= keep; acc.z *= keep; acc.w *= keep;
            f4store(&s_attnout[qi][j], acc);
        }
        __syncthreads();
        if (tid < 64) {
            const float* W4 = fc2_w + i * HYPD * 32;
            const float* B4 = fc2_b + i * 32;
            int qi = tid >> 3, c = (tid & 7) * 4;
            float4 acc = f4load(B4 + c);
            for (int d = 0; d < HYPD; ++d) f4fma(acc, s_attnout[qi][d], f4load(W4 + d * 32 + c));
            float keep = 1.f - s_mask[qi];
            acc.x *= keep; acc.y *= keep; acc.z *= keep; acc.w *= keep;
            f4store(&s_outs[i][qi][c], acc);
        }
        __syncthreads();
    }

    if (tid < 32) {
        const int c = tid;
        float b1 = 0.f, s1 = 0.f, vs = 0.f;
        #pragma unroll
        for (int qi = 0; qi < NAG; ++qi) {
            b1 += s_outs[2][qi][c]; s1 += s_outs[1][qi][c]; vs += s_outs[3][qi][c];
        }
        b1 *= 0.125f; s1 *= 0.125f;
        float hid = 0.f;
        #pragma unroll
        for (int a = 0; a < NAG; ++a) {
            float x = s_outs[0][a][c];
            float mx = x;
            #pragma unroll
            for (int m = 16; m >= 1; m >>= 1) mx = fmaxf(mx, __shfl_xor(mx, m, 32));
            float e = __expf(x - mx);
            float sm = e;
            #pragma unroll
            for (int m = 16; m >= 1; m >>= 1) sm += __shfl_xor(sm, m, 32);
            hid += s_qs[a] * (e / sm);
        }
        hid += b1;
        hid = (hid > 0.f) ? hid : expm1f(hid);
        float mx = s1;
        #pragma unroll
        for (int m = 16; m >= 1; m >>= 1) mx = fmaxf(mx, __shfl_xor(mx, m, 32));
        float e = __expf(s1 - mx);
        float ssum = e;
        #pragma unroll
        for (int m = 16; m >= 1; m >>= 1) ssum += __shfl_xor(ssum, m, 32);
        float wf = e / ssum;
        float red = hid * wf + vs * (1.f / 256.f);
        #pragma unroll
        for (int m = 16; m >= 1; m >>= 1) red += __shfl_xor(red, m, 32);
        if (tid == 0) out[b] = red;
    }
}

extern "C" void kernel_launch(void* const* d_in, const int* in_sizes, int n_in,
                              void* d_out, int out_size, void* d_ws, size_t ws_size,
                              hipStream_t stream) {
    const float* agent_qs    = (const float*)d_in[0];
    const float* entities    = (const float*)d_in[1];
    const int*   entity_mask = (const int*)  d_in[2];
    const float* fc1_w       = (const float*)d_in[3];
    const float* fc1_b       = (const float*)d_in[4];
    const float* attn_w      = (const float*)d_in[5];
    const float* out_w       = (const float*)d_in[6];
    const float* out_b       = (const float*)d_in[7];
    const float* fc2_w       = (const float*)d_in[8];
    const float* fc2_b       = (const float*)d_in[9];
    float* out = (float*)d_out;

    const int B = in_sizes[0] / NAG;  // 8192

    if (ws_size >= (size_t)(608 * 1024) && (B % SB) == 0) {
        pack_weights<<<152, 256, 0, stream>>>(fc1_w, attn_w, out_w, fc2_w, (short*)d_ws);
        flexq_mfma<<<B / SB, 256, 0, stream>>>(agent_qs, entities, entity_mask,
                                               fc1_b, out_b, fc2_b,
                                               (const short*)d_ws, out, B);
    } else {
        flexq_fp32<<<B, NTHR, 0, stream>>>(agent_qs, entities, entity_mask,
                                           fc1_w, fc1_b, attn_w, out_w, out_b,
                                           fc2_w, fc2_b, out);
    }
}